// Round 1
// baseline (820.583 us; speedup 1.0000x reference)
//
#include <hip/hip_runtime.h>
#include <hip/hip_bf16.h>
#include <stdint.h>
#include <stddef.h>

typedef __attribute__((ext_vector_type(8))) short bf16x8;
typedef __attribute__((ext_vector_type(4))) short bf16x4;
typedef __attribute__((ext_vector_type(4))) float f32x4;

__device__ __forceinline__ unsigned short f2bf(float x) {
    union { float f; unsigned u; } v; v.f = x;
    unsigned r = v.u + 0x7fffu + ((v.u >> 16) & 1u);   // round-to-nearest-even
    return (unsigned short)(r >> 16);
}
__device__ __forceinline__ float bf2f(unsigned short h) {
    union { unsigned u; float f; } v; v.u = ((unsigned)h) << 16;
    return v.f;
}

// ---- transpose + convert weights: WT[n][k] = bf16(W[k][n]) ----
extern "C" __global__ void prep_w_kernel(const float* __restrict__ Wp, const float* __restrict__ Ws,
                                         unsigned short* __restrict__ WpT, unsigned short* __restrict__ WsT,
                                         int Cin, int Cs, int Cout)
{
    int tid = blockIdx.x * blockDim.x + threadIdx.x;
    int np = Cin * Cout;
    int ns = Cs * Cout;
    if (tid < np) {
        int k = tid / Cout, n = tid - k * Cout;
        WpT[n * Cin + k] = f2bf(Wp[tid]);
    } else if (tid < np + ns) {
        int t = tid - np;
        int k = t / Cout, n = t - k * Cout;
        WsT[n * Cs + k] = f2bf(Ws[t]);
    }
}

// ---- 128x128 bf16 MFMA GEMM: outb = bf16(A @ W + bias), plus per-channel sum/sumsq ----
// A: [M,K] fp32 row-major.  WT: [N,K] bf16 (W transposed).  outb: [M,N] bf16.
// grid = (M/128, N/128), block = 256 (4 waves; wave w covers 64x64 at (w>>1, w&1)).
extern "C" __global__ __launch_bounds__(256, 2)
void gemm_bn_kernel(const float* __restrict__ A, const unsigned short* __restrict__ WT,
                    const float* __restrict__ bias,
                    unsigned short* __restrict__ outb,
                    float* __restrict__ gsum, float* __restrict__ gsumsq,
                    int M, int K, int N)
{
    const int m0 = blockIdx.x * 128;
    const int n0 = blockIdx.y * 128;
    const int tid = threadIdx.x;
    const int lane = tid & 63;
    const int wave = tid >> 6;
    const int wm = (wave >> 1) << 6;
    const int wn = (wave & 1) << 6;
    const int q = lane >> 4;       // quad index 0..3
    const int l15 = lane & 15;

    // rows padded 32 -> 40 bf16 (80 B stride: keeps 16 B alignment, breaks pow2 banks)
    __shared__ unsigned short sA[128 * 40];
    __shared__ unsigned short sB[128 * 40];

    f32x4 acc[4][4];
#pragma unroll
    for (int i = 0; i < 4; ++i)
#pragma unroll
        for (int j = 0; j < 4; ++j)
            acc[i][j] = (f32x4){0.f, 0.f, 0.f, 0.f};

    // A staging: 1024 float4 chunks per k-tile; thread t gets chunks t + 256r
    const int a_m = tid >> 3;      // 0..31 (+32r)
    const int a_f = tid & 7;       // float4 index in 32-float row segment
    // B staging: 512 16B chunks; thread t gets chunks t + 256r
    const int b_n = tid >> 2;      // 0..63 (+64r)
    const int b_seg = tid & 3;     // 8-bf16 segment in 32-elem row

    const float* Abase = A + (size_t)(m0 + a_m) * K + a_f * 4;
    const unsigned short* Bbase = WT + (size_t)(n0 + b_n) * K + b_seg * 8;

    const int ksteps = K >> 5;
    for (int kt = 0; kt < ksteps; ++kt) {
        const int k0 = kt << 5;
        __syncthreads();
#pragma unroll
        for (int r = 0; r < 4; ++r) {
            f32x4 av = *(const f32x4*)(Abase + (size_t)(32 * r) * K + k0);
            bf16x4 pk;
            pk[0] = (short)f2bf(av[0]); pk[1] = (short)f2bf(av[1]);
            pk[2] = (short)f2bf(av[2]); pk[3] = (short)f2bf(av[3]);
            *(bf16x4*)(&sA[(a_m + 32 * r) * 40 + a_f * 4]) = pk;
        }
#pragma unroll
        for (int r = 0; r < 2; ++r) {
            bf16x8 wv = *(const bf16x8*)(Bbase + (size_t)(64 * r) * K + k0);
            *(bf16x8*)(&sB[(b_n + 64 * r) * 40 + b_seg * 8]) = wv;
        }
        __syncthreads();

        bf16x8 afr[4], bfr[4];
#pragma unroll
        for (int mi = 0; mi < 4; ++mi)
            afr[mi] = *(const bf16x8*)(&sA[(wm + mi * 16 + l15) * 40 + q * 8]);
#pragma unroll
        for (int ni = 0; ni < 4; ++ni)
            bfr[ni] = *(const bf16x8*)(&sB[(wn + ni * 16 + l15) * 40 + q * 8]);
#pragma unroll
        for (int mi = 0; mi < 4; ++mi)
#pragma unroll
            for (int ni = 0; ni < 4; ++ni)
                acc[mi][ni] = __builtin_amdgcn_mfma_f32_16x16x32_bf16(afr[mi], bfr[ni], acc[mi][ni], 0, 0, 0);
    }

    // epilogue: +bias, store bf16, per-channel stats (C/D map: col=lane&15, row=q*4+reg)
#pragma unroll
    for (int ni = 0; ni < 4; ++ni) {
        const int c = n0 + wn + ni * 16 + l15;
        const float bv = bias[c];
        float s1 = 0.f, s2 = 0.f;
#pragma unroll
        for (int mi = 0; mi < 4; ++mi) {
            const int row = m0 + wm + mi * 16 + (q << 2);
#pragma unroll
            for (int r = 0; r < 4; ++r) {
                float v = acc[mi][ni][r] + bv;
                s1 += v; s2 += v * v;
                outb[(size_t)(row + r) * N + c] = f2bf(v);
            }
        }
        // lanes L, L^16, L^32, L^48 share column c -> reduce over quads
        s1 += __shfl_xor(s1, 16); s2 += __shfl_xor(s2, 16);
        s1 += __shfl_xor(s1, 32); s2 += __shfl_xor(s2, 32);
        if (q == 0) {
            atomicAdd(&gsum[c], s1);
            atomicAdd(&gsumsq[c], s2);
        }
    }
}

// ---- per-channel BN affine: a = gamma*rsqrt(var+eps), b = beta - mean*a ----
extern "C" __global__ void finalize_kernel(const float* __restrict__ stats,
                                           const float* __restrict__ gamma_p, const float* __restrict__ beta_p,
                                           const float* __restrict__ gamma_s, const float* __restrict__ beta_s,
                                           float* __restrict__ ab, float invNp, float invNs, int Cout)
{
    int c = threadIdx.x;
    if (c < Cout) {
        float m = stats[c] * invNp;
        float var = stats[Cout + c] * invNp - m * m;
        float a = gamma_p[c] * rsqrtf(var + 1e-5f);
        ab[c] = a;
        ab[Cout + c] = beta_p[c] - m * a;
        float m2 = stats[2 * Cout + c] * invNs;
        float var2 = stats[3 * Cout + c] * invNs - m2 * m2;
        float a2 = gamma_s[c] * rsqrtf(var2 + 1e-5f);
        ab[2 * Cout + c] = a2;
        ab[3 * Cout + c] = beta_s[c] - m2 * a2;
    }
}

// ---- out[i,c] = relu(h[cluster[i],c]*ap+bp) + relu(s[i,c]*as+bs) ----
// assumes Cout == 256 (64 threads of 4 channels per point)
extern "C" __global__ __launch_bounds__(256)
void fuse_kernel(const unsigned short* __restrict__ hb, const unsigned short* __restrict__ sb,
                 const int* __restrict__ cluster, const float* __restrict__ ab,
                 float* __restrict__ out, int Cout)
{
    int idx = blockIdx.x * 256 + threadIdx.x;
    int i = idx >> 6;
    int c4 = (idx & 63) << 2;
    int j = cluster[i];
    bf16x4 h4 = *(const bf16x4*)(hb + (size_t)j * Cout + c4);
    bf16x4 s4 = *(const bf16x4*)(sb + (size_t)i * Cout + c4);
    f32x4 ap = *(const f32x4*)(ab + c4);
    f32x4 bp = *(const f32x4*)(ab + Cout + c4);
    f32x4 as = *(const f32x4*)(ab + 2 * Cout + c4);
    f32x4 bs = *(const f32x4*)(ab + 3 * Cout + c4);
    f32x4 o;
#pragma unroll
    for (int e = 0; e < 4; ++e) {
        float hv = bf2f((unsigned short)h4[e]) * ap[e] + bp[e];
        float sv = bf2f((unsigned short)s4[e]) * as[e] + bs[e];
        o[e] = fmaxf(hv, 0.f) + fmaxf(sv, 0.f);
    }
    *(f32x4*)(out + (size_t)i * Cout + c4) = o;
}

extern "C" void kernel_launch(void* const* d_in, const int* in_sizes, int n_in,
                              void* d_out, int out_size, void* d_ws, size_t ws_size,
                              hipStream_t stream)
{
    const float* feat    = (const float*)d_in[0];
    const float* skipf   = (const float*)d_in[1];
    const int*   cluster = (const int*)d_in[2];
    const float* W_proj  = (const float*)d_in[3];
    const float* b_proj  = (const float*)d_in[4];
    const float* gamma_p = (const float*)d_in[5];
    const float* beta_p  = (const float*)d_in[6];
    const float* W_skip  = (const float*)d_in[7];
    const float* b_skip  = (const float*)d_in[8];
    const float* gamma_s = (const float*)d_in[9];
    const float* beta_s  = (const float*)d_in[10];
    float* out = (float*)d_out;

    const int Cout = in_sizes[4];            // 256
    const int Cin  = in_sizes[3] / Cout;     // 512
    const int Cs   = in_sizes[7] / Cout;     // 256
    const int Nout = in_sizes[2];            // 262144
    const int Nin  = in_sizes[0] / Cin;      // 65536

    // workspace layout (all offsets 16B-aligned)
    char* ws = (char*)d_ws;
    unsigned short* h_pre = (unsigned short*)ws; ws += (size_t)Nin * Cout * 2;   // 32 MiB
    unsigned short* s_pre = (unsigned short*)ws; ws += (size_t)Nout * Cout * 2;  // 128 MiB
    unsigned short* WpT   = (unsigned short*)ws; ws += (size_t)Cout * Cin * 2;   // 256 KiB
    unsigned short* WsT   = (unsigned short*)ws; ws += (size_t)Cout * Cs * 2;    // 128 KiB
    float* stats          = (float*)ws;          ws += (size_t)4 * Cout * 4;     // 4 KiB
    float* ab             = (float*)ws;                                          // 4 KiB

    hipMemsetAsync(stats, 0, 4 * Cout * sizeof(float), stream);

    int prep_total = Cin * Cout + Cs * Cout;
    prep_w_kernel<<<(prep_total + 255) / 256, 256, 0, stream>>>(W_proj, W_skip, WpT, WsT, Cin, Cs, Cout);

    dim3 g1(Nin / 128, Cout / 128);
    gemm_bn_kernel<<<g1, 256, 0, stream>>>(feat, WpT, b_proj, h_pre,
                                           stats, stats + Cout, Nin, Cin, Cout);

    dim3 g2(Nout / 128, Cout / 128);
    gemm_bn_kernel<<<g2, 256, 0, stream>>>(skipf, WsT, b_skip, s_pre,
                                           stats + 2 * Cout, stats + 3 * Cout, Nout, Cs, Cout);

    finalize_kernel<<<1, Cout, 0, stream>>>(stats, gamma_p, beta_p, gamma_s, beta_s,
                                            ab, 1.0f / (float)Nin, 1.0f / (float)Nout, Cout);

    size_t total_threads = (size_t)Nout * (Cout / 4);
    fuse_kernel<<<(unsigned)(total_threads / 256), 256, 0, stream>>>(h_pre, s_pre, cluster, ab, out, Cout);
}